// Round 8
// baseline (412.772 us; speedup 1.0000x reference)
//
#include <hip/hip_runtime.h>

#define N_ROWS 131072
#define DIM 64
#define K_CODES 4096
#define BROWS 256            // rows per block = 8 waves x 32
#define CK 64                // cols per chunk
#define NCH (K_CODES / CK)   // 64 chunks
#define EST 72               // LDS bf16 stride (64 + 8 pad) -> bank-balanced frags
#define EPS 0.015625f        // flag margin in score space (>=15x bf16x3 error bound)
#define HEPS 0.0078125f      // EPS/2 in d-space (score = -2*d + const)

typedef __attribute__((ext_vector_type(8))) short short8;
typedef __attribute__((ext_vector_type(4))) float f32x4;

__device__ inline unsigned short bf16rn(float f) {      // round-nearest-even
    unsigned int u = __float_as_uint(f);
    u += 0x7FFFu + ((u >> 16) & 1u);
    return (unsigned short)(u >> 16);
}
// order-preserving float -> uint32 (finite scores)
__device__ inline unsigned int fkey(float f) {
    unsigned int u = __float_as_uint(f);
    return (u & 0x80000000u) ? ~u : (u | 0x80000000u);
}

// ---- pack embed -> bf16 hi/lo [code][hi 64 | lo 64], plus e2 / -e2/2, plus
//      zero-fill of cnt and the cs/esum output stats.
// Plain row-major, no swizzle: LDS contents in dist stay BIT-IDENTICAL to the
// proven round-4..7 kernels (rounds 1-3's swizzled staging inflated the
// ambiguity-flag count ~100x -> that path stays dead).
__global__ void pack_kernel(const float* __restrict__ embed,
                            unsigned short* __restrict__ ebf,
                            float* __restrict__ e2,       // exact, for refine
                            float* __restrict__ e2h,      // -e2/2, for dist init
                            int* __restrict__ cnt,
                            float* __restrict__ cs) {     // cs..esum contiguous
    const int g = blockIdx.x * blockDim.x + threadIdx.x;   // K*16 = 65536 thr
    // zero stats: cs [K] followed contiguously by esum [K*D]
    for (int i = g; i < K_CODES + K_CODES * DIM; i += K_CODES * 16)
        cs[i] = 0.f;
    if (g == 0) *cnt = 0;

    const int code = g >> 4;                               // 16 granules / code
    const int w    = g & 15;
    const int half = w >> 3;                               // 0 = hi, 1 = lo
    const int d0   = (w & 7) << 3;                         // dim 0..56
    const float* ep = embed + (size_t)code * DIM + d0;
    float4 f0 = *(const float4*)ep;
    float4 f1 = *(const float4*)(ep + 4);
    float wv[8] = {f0.x, f0.y, f0.z, f0.w, f1.x, f1.y, f1.z, f1.w};
    unsigned short o[8];
    float ssq = 0.f;
#pragma unroll
    for (int j = 0; j < 8; ++j) {
        unsigned short hb = bf16rn(wv[j]);
        if (half == 0) {
            o[j] = hb;
            ssq = fmaf(wv[j], wv[j], ssq);
        } else {
            float hf = __uint_as_float(((unsigned int)hb) << 16);
            o[j] = bf16rn(wv[j] - hf);
        }
    }
    *(uint4*)(ebf + (size_t)code * 128 + half * 64 + d0) = *(uint4*)o;
    // e2: reduce ssq across the 8 hi-granule lanes of this code
    ssq += __shfl_xor(ssq, 1, 64);
    ssq += __shfl_xor(ssq, 2, 64);
    ssq += __shfl_xor(ssq, 4, 64);
    if (w == 0) {
        e2[code]  = ssq;
        e2h[code] = -0.5f * ssq;
    }
}

// ---- MFMA distance + fused top-2 argmax(d), d = x.e - e2/2 ----
// r8 change: 8 waves x 32 rows (was 4 x 64) -> 16 waves/CU (50% occupancy,
// was 19%) to fill the per-chunk barrier drains. Per-score math, LDS image,
// epilogue, flag rule all bit-identical; only the wave decomposition changes.
__global__ __launch_bounds__(512, 4) void dist_argmin_kernel(
        const float* __restrict__ x, const unsigned short* __restrict__ ebf,
        const float* __restrict__ e2h, const float* __restrict__ embed,
        int* __restrict__ ind_ws, float* __restrict__ ind_out,
        int* __restrict__ cnt, int* __restrict__ list,
        float* __restrict__ quant, float* __restrict__ cs,
        float* __restrict__ esum, int fused) {
    __shared__ unsigned short esh[2][CK * EST];   // 2 x 9216 B
    __shared__ unsigned short esl[2][CK * EST];   // 2 x 9216 B
    __shared__ float e2s[2][CK];                  // holds -e2/2

    const int tid  = threadIdx.x;
    const int l15  = tid & 15;
    const int quad = (tid >> 4) & 3;
    const int wave = tid >> 6;                    // 0..7
    const int r0w  = blockIdx.x * BROWS + wave * 32;

    const int col = tid >> 3;          // staging: code within chunk (0..63)
    const int dq  = (tid & 7) * 8;     // staging: dim offset (8 bf16 = 16 B)

    // ---- prologue: issue chunk-0 global loads FIRST (fly under A-frag conv)
    uint4 sh0, sl0;
    float se2 = 0.f;
    {
        const unsigned short* pp = ebf + (size_t)col * 128 + dq;
        sh0 = *(const uint4*)pp;          // hi granule
        sl0 = *(const uint4*)(pp + 64);   // lo granule
        if (tid < CK) se2 = e2h[tid];
    }

    // A-frags: A[m=l15][k=quad*8+j] per 16x16x32; rows 16i+l15, k-windows 32s+8q
    short8 ah[2][2], al[2][2];
#pragma unroll
    for (int i = 0; i < 2; ++i)
#pragma unroll
        for (int s = 0; s < 2; ++s) {
            const float* xp = x + (size_t)(r0w + 16 * i + l15) * DIM + 32 * s + 8 * quad;
            float4 f0 = *(const float4*)xp;
            float4 f1 = *(const float4*)(xp + 4);
            float w[8] = {f0.x, f0.y, f0.z, f0.w, f1.x, f1.y, f1.z, f1.w};
            short8 h, l;
#pragma unroll
            for (int j = 0; j < 8; ++j) {
                unsigned short hb = bf16rn(w[j]);
                float hf = __uint_as_float(((unsigned int)hb) << 16);
                h[j] = (short)hb;
                l[j] = (short)bf16rn(w[j] - hf);
            }
            ah[i][s] = h;
            al[i][s] = l;
        }

    // write chunk 0 into buffer 0
    *(uint4*)(&esh[0][col * EST + dq]) = sh0;
    *(uint4*)(&esl[0][col * EST + dq]) = sl0;
    if (tid < CK) e2s[0][tid] = se2;

    float s1[8], s2[8];
    int c1[8];
#pragma unroll
    for (int t = 0; t < 8; ++t) { s1[t] = -3.4e38f; s2[t] = -3.4e38f; c1[t] = 0; }

    __syncthreads();   // buffer 0 ready

    int cur = 0;
    for (int ch = 0; ch < NCH; ++ch) {
        // ---- issue next chunk's global loads early (wraps to 0 harmlessly)
        {
            const int c0n = ((ch + 1) & (NCH - 1)) * CK;
            const unsigned short* pp = ebf + (size_t)(c0n + col) * 128 + dq;
            sh0 = *(const uint4*)pp;
            sl0 = *(const uint4*)(pp + 64);
            if (tid < CK) se2 = e2h[c0n + tid];
        }

        const int c0 = ch * CK;

        // acc init = -e2[col]/2 (C/D col = l15 per 16-tile j)
        f32x4 acc[2][4];
#pragma unroll
        for (int j = 0; j < 4; ++j) {
            const float ev = e2s[cur][16 * j + l15];
            const f32x4 iv = {ev, ev, ev, ev};
#pragma unroll
            for (int i = 0; i < 2; ++i) acc[i][j] = iv;
        }

#pragma unroll
        for (int j = 0; j < 4; ++j) {
            const int cb = (16 * j + l15) * EST + 8 * quad;   // B[n=l15][k=8q+j]
            short8 bh0 = *(const short8*)(&esh[cur][cb]);
            short8 bh1 = *(const short8*)(&esh[cur][cb + 32]);
            short8 bl0 = *(const short8*)(&esl[cur][cb]);
            short8 bl1 = *(const short8*)(&esl[cur][cb + 32]);
#pragma unroll
            for (int i = 0; i < 2; ++i) {
                f32x4 a = acc[i][j];
                a = __builtin_amdgcn_mfma_f32_16x16x32_bf16(ah[i][0], bh0, a, 0, 0, 0);
                a = __builtin_amdgcn_mfma_f32_16x16x32_bf16(ah[i][1], bh1, a, 0, 0, 0);
                a = __builtin_amdgcn_mfma_f32_16x16x32_bf16(ah[i][0], bl0, a, 0, 0, 0);
                a = __builtin_amdgcn_mfma_f32_16x16x32_bf16(ah[i][1], bl1, a, 0, 0, 0);
                a = __builtin_amdgcn_mfma_f32_16x16x32_bf16(al[i][0], bh0, a, 0, 0, 0);
                a = __builtin_amdgcn_mfma_f32_16x16x32_bf16(al[i][1], bh1, a, 0, 0, 0);
                acc[i][j] = a;
            }
        }

        // epilogue (proven): argmax d, clamp-idiom second-max
#pragma unroll
        for (int j = 0; j < 4; ++j) {
            const int c = c0 + 16 * j + l15;
#pragma unroll
            for (int i = 0; i < 2; ++i)
#pragma unroll
                for (int r = 0; r < 4; ++r) {
                    float d = acc[i][j][r];
                    const int st = i * 4 + r;
                    bool gt = d > s1[st];
                    s2[st] = fmaxf(fminf(d, s1[st]), s2[st]);
                    c1[st] = gt ? c : c1[st];
                    s1[st] = fmaxf(s1[st], d);
                }
        }

        // ---- write next chunk into the inactive buffer
        const int nxt = cur ^ 1;
        *(uint4*)(&esh[nxt][col * EST + dq]) = sh0;
        *(uint4*)(&esl[nxt][col * EST + dq]) = sl0;
        if (tid < CK) e2s[nxt][tid] = se2;

        __syncthreads();   // next buffer visible; all waves done with cur
        cur = nxt;
    }

    // butterfly top-2 merge across the 16 lanes (same quad) sharing each row
#pragma unroll
    for (int st = 0; st < 8; ++st) {
#pragma unroll
        for (int m = 1; m < 16; m <<= 1) {
            float os1 = __shfl_xor(s1[st], m, 64);
            float os2 = __shfl_xor(s2[st], m, 64);
            int   oc1 = __shfl_xor(c1[st], m, 64);
            bool take = (os1 > s1[st]) || (os1 == s1[st] && oc1 < c1[st]);
            float loser = take ? s1[st] : os1;
            s2[st] = fmaxf(fmaxf(s2[st], os2), loser);
            if (take) { s1[st] = os1; c1[st] = oc1; }
        }
    }
    if (l15 == 0) {
#pragma unroll
        for (int st = 0; st < 8; ++st) {
            const int i = st >> 2, r = st & 3;
            const int row = r0w + 16 * i + 4 * quad + r;
            ind_ws[row] = c1[st];
            ind_out[row] = (float)c1[st];
            if (s1[st] - s2[st] < HEPS) {    // d-gap = score-gap/2 < EPS/2
                int p = atomicAdd(cnt, 1);
                list[p] = row;
            }
        }
    }

    // ---- fused gather/scatter epilogue (replaces scatter_kernel) ----
    // All waves are past the final barrier; esh is dead -> reuse as an
    // intra-wave index board (each wave touches only its own 128 B).
    if (fused) {
        int* li = (int*)&esh[0][0];
        if (l15 == 0) {
#pragma unroll
            for (int st = 0; st < 8; ++st) {
                const int i = st >> 2, r = st & 3;
                li[(wave << 5) + 16 * i + 4 * quad + r] = c1[st];
            }
        }
        const int lane = tid & 63;
        for (int t = 0; t < 32; ++t) {
            const int k = li[(wave << 5) + t];   // wave-uniform broadcast read
            const size_t row = (size_t)(r0w + t);
            quant[row * DIM + lane] = embed[(size_t)k * DIM + lane];
            float xv = x[row * DIM + lane];      // L3-hot (read earlier)
            atomicAdd(&esum[(size_t)k * DIM + lane], xv);
            if (lane == 0) atomicAdd(&cs[k], 1.0f);
        }
    }
}

// ---- exact fp32 re-solve for flagged rows (block per row, round-0 proven) ----
// fused mode: also FIX UP quant/cs/esum for rows whose index changed
// (subtract old contribution, add new; x row is in LDS, exact fp32).
__global__ void refine_kernel(const float* __restrict__ x,
                              const float* __restrict__ embed,
                              const float* __restrict__ e2g,
                              const int* __restrict__ cnt,
                              const int* __restrict__ list,
                              int* __restrict__ ind_ws,
                              float* __restrict__ ind_out,
                              float* __restrict__ quant,
                              float* __restrict__ cs,
                              float* __restrict__ esum, int fused) {
    __shared__ float xr[DIM];
    __shared__ unsigned long long red[256];
    const int tid = threadIdx.x;
    const int n = *cnt;
    for (int f = blockIdx.x; f < n; f += gridDim.x) {
        const int row = list[f];
        __syncthreads();
        if (tid < 16)
            ((float4*)xr)[tid] = ((const float4*)(x + (size_t)row * DIM))[tid];
        __syncthreads();
        unsigned long long best = ~0ull;
        for (int c = tid; c < K_CODES; c += 256) {
            const float4* ep = (const float4*)(embed + (size_t)c * DIM);
            float d0 = 0.f, d1 = 0.f, d2 = 0.f, d3 = 0.f;
#pragma unroll
            for (int q = 0; q < 16; ++q) {
                float4 ev = ep[q];
                d0 = fmaf(xr[4 * q + 0], ev.x, d0);
                d1 = fmaf(xr[4 * q + 1], ev.y, d1);
                d2 = fmaf(xr[4 * q + 2], ev.z, d2);
                d3 = fmaf(xr[4 * q + 3], ev.w, d3);
            }
            float sc = fmaf(-2.f, (d0 + d1) + (d2 + d3), e2g[c]);
            unsigned long long key =
                ((unsigned long long)fkey(sc) << 32) | (unsigned int)c;
            if (key < best) best = key;
        }
        red[tid] = best;
        __syncthreads();
        for (int w = 128; w > 0; w >>= 1) {
            if (tid < w && red[tid + w] < red[tid]) red[tid] = red[tid + w];
            __syncthreads();
        }
        const int k_new = (int)(red[0] & 0xFFFFFFFFull);
        if (fused) {
            const int k_old = ind_ws[row];
            if (k_new != k_old) {
                if (tid < DIM) {
                    float xv = xr[tid];
                    atomicAdd(&esum[(size_t)k_old * DIM + tid], -xv);
                    atomicAdd(&esum[(size_t)k_new * DIM + tid],  xv);
                    quant[(size_t)row * DIM + tid] =
                        embed[(size_t)k_new * DIM + tid];
                }
                if (tid == 0) {
                    atomicAdd(&cs[k_old], -1.f);
                    atomicAdd(&cs[k_new],  1.f);
                    ind_ws[row] = k_new;
                    ind_out[row] = (float)k_new;
                }
            }
        } else if (tid == 0) {
            ind_ws[row] = k_new;
            ind_out[row] = (float)k_new;
        }
    }
}

// ---- gather quantize + scatter stats (fallback only, one wave = one row) ----
__global__ void scatter_kernel(const float* __restrict__ x,
                               const float* __restrict__ embed,
                               const int* __restrict__ ind,
                               float* __restrict__ quant,
                               float* __restrict__ cs,
                               float* __restrict__ esum) {
    const int t = blockIdx.x * blockDim.x + threadIdx.x;
    const int row = t >> 6;
    const int d = t & 63;
    const int k = ind[row];
    quant[t] = embed[(size_t)k * DIM + d];
    atomicAdd(&esum[(size_t)k * DIM + d], x[t]);
    if (d == 0) atomicAdd(&cs[k], 1.0f);
}

extern "C" void kernel_launch(void* const* d_in, const int* in_sizes, int n_in,
                              void* d_out, int out_size, void* d_ws, size_t ws_size,
                              hipStream_t stream) {
    const float* x     = (const float*)d_in[0];
    const float* embed = (const float*)d_in[1];

    float* out     = (float*)d_out;
    float* quant   = out;                            // [N, D]
    float* ind_out = out + (size_t)N_ROWS * DIM;     // [N] (as float)
    float* cs      = ind_out + N_ROWS;               // [K]
    float* esum    = cs + K_CODES;                   // [K, D]  (contiguous w/ cs)

    // ws: e2 [K] | cnt [4] | list [N] | ind_ws [N] | e2h [K] | ebf [K*128 u16]
    float* e2   = (float*)d_ws;
    int* cnt    = (int*)(e2 + K_CODES);
    int* list   = cnt + 4;
    int* ind_ws = list + N_ROWS;
    float* e2h  = (float*)(ind_ws + N_ROWS);
    unsigned short* ebf_ws = (unsigned short*)(e2h + K_CODES);
    const size_t ws_need =
        (size_t)((char*)(ebf_ws + (size_t)K_CODES * 128) - (char*)d_ws);

    // fused mode needs ebf in ws (dist's fused epilogue writes the quant
    // region, which is where the fallback parks ebf). Host-side check; the
    // fallback path is the round-6 behavior.
    const int fused = (ws_size >= ws_need) ? 1 : 0;
    unsigned short* ebf = fused ? ebf_ws : (unsigned short*)quant;

    pack_kernel<<<(K_CODES * 16) / 256, 256, 0, stream>>>(
        embed, ebf, e2, e2h, cnt, cs);
    dist_argmin_kernel<<<N_ROWS / BROWS, 512, 0, stream>>>(
        x, ebf, e2h, embed, ind_ws, ind_out, cnt, list, quant, cs, esum, fused);
    refine_kernel<<<512, 256, 0, stream>>>(
        x, embed, e2, cnt, list, ind_ws, ind_out, quant, cs, esum, fused);
    if (!fused)
        scatter_kernel<<<(size_t)N_ROWS * DIM / 256, 256, 0, stream>>>(
            x, embed, ind_ws, quant, cs, esum);
}